// Round 8
// baseline (14.137 us; speedup 1.0000x reference)
//
#include <hip/hip_runtime.h>
#include <math.h>

// Shapelet distance + softmin pooling.
// x: (8, 8, 2048) f32, w: (32, 8, 32) f32
// out: [pred (8*256), d_min (8*256)] f32
//
// d2(b,t,n,m) = x2(t) + w2 - 2*dot(t)   (>= 0; clip no-op)
// pred = exp(-d2min + log(sum_t exp(-10*d2))/10);  dmin = sqrt(d2min)
//
// Round 8: ROLLING-WINDOW restructure. Rounds 3-7 showed ~8us marginal kernel
// time vs ~2.7us issue floor with xs[40] fully live across the dot loop ->
// spill-bound regardless of launch_bounds/waves_per_eu/SGPR-weights tweaks.
// Here each float4 group is consumed on arrival (dot chains + running ss +
// 14 retained scalars for sliding-x2), peak liveness ~45 VGPR -> no spills
// under ANY allocator budget choice.

#define T_VALID 2017
#define K10 14.426950408889634f   // 10 / ln(2):  exp(10*z) == exp2(K10*z)

__global__ __launch_bounds__(1024)
__attribute__((amdgpu_waves_per_eu(4, 4)))
void shapelet_kernel(
    const float* __restrict__ x,
    const float* __restrict__ w,
    float* __restrict__ out)
{
    const int bid = blockIdx.x;
    const int b = bid >> 5;       // 0..7
    const int n = bid & 31;       // 0..31
    const int tid = threadIdx.x;
    const int m = tid >> 7;       // 0..7, uniform per wave
    const int tq = tid & 127;     // 0..127

    // weights for (n, m): wave-uniform -> scalar loads, SGPR-resident
    const int mu = __builtin_amdgcn_readfirstlane(m);
    const float* __restrict__ wp = w + (((n << 3) + mu) << 5);
    float wr[32];
    #pragma unroll
    for (int l = 0; l < 32; ++l) wr[l] = wp[l];
    float w2c = 0.0f;
    #pragma unroll
    for (int l = 0; l < 32; ++l) w2c = fmaf(wr[l], wr[l], w2c);

    // x row for (b, m): 2048 floats = 512 float4
    const float4* x4 = reinterpret_cast<const float4*>(x + (((b << 3) + m) << 11));

    float mrun = INFINITY;  // running min d2
    float S = 0.0f;         // sum_t exp2(K10*(mrun - d2))

    // Each thread: 8 consecutive t per k-iter; tt = k*128 + tq.
    // k=0 is fully valid for every thread (t0 <= 1016), so mrun is finite
    // before any masked (INFINITY) tail lanes appear in k=1.
    #pragma unroll 1
    for (int k = 0; k < 2; ++k) {
        const int tt = (k << 7) + tq;
        const int base = tt << 1;           // float4 index of window start
        float dv[8];
        #pragma unroll
        for (int dt = 0; dt < 8; ++dt) dv[dt] = 0.0f;
        float ss = 0.0f;                    // sum_{l=0..31} xs[l]^2
        float keep_lo[7], keep_hi[7];       // xs[0..6], xs[32..38]

        // stream 10 float4 groups; consume each immediately
        #pragma unroll
        for (int j = 0; j < 10; ++j) {
            int idx = base + j;
            idx = idx > 511 ? 511 : idx;    // clamp (feeds only masked t)
            const float4 v = x4[idx];
            float g[4] = {v.x, v.y, v.z, v.w};
            #pragma unroll
            for (int i = 0; i < 4; ++i) {
                const int p = 4 * j + i;    // window-relative element index
                if (p < 32) ss = fmaf(g[i], g[i], ss);
                if (p < 7) keep_lo[p] = g[i];
                if (p >= 32 && p < 39) keep_hi[p - 32] = g[i];
                #pragma unroll
                for (int dt = 0; dt < 8; ++dt) {
                    const int l = p - dt;
                    if (l >= 0 && l < 32)
                        dv[dt] = fmaf(g[i], wr[l], dv[dt]);
                }
            }
        }

        // d2 per dt via sliding x2, masked tail -> +inf
        const int t0 = tt << 3;
        float d2[8];
        float x2 = ss;
        d2[0] = fmaf(-2.0f, dv[0], x2 + w2c);
        #pragma unroll
        for (int dt = 1; dt < 8; ++dt) {
            x2 = fmaf(keep_hi[dt - 1], keep_hi[dt - 1], x2)
                 - keep_lo[dt - 1] * keep_lo[dt - 1];
            d2[dt] = fmaf(-2.0f, dv[dt], x2 + w2c);
        }
        #pragma unroll
        for (int dt = 0; dt < 8; ++dt)
            if (t0 + dt >= T_VALID) d2[dt] = INFINITY;

        // online softmin update (one rescale per 8-t tile)
        float tmin = d2[0];
        #pragma unroll
        for (int dt = 1; dt < 8; ++dt) tmin = fminf(tmin, d2[dt]);
        const float nm = fminf(mrun, tmin);
        float s_tile = 0.0f;
        #pragma unroll
        for (int dt = 0; dt < 8; ++dt)
            s_tile += exp2f(K10 * (nm - d2[dt]));
        S = fmaf(S, exp2f(K10 * (nm - mrun)), s_tile);
        mrun = nm;
    }

    // --- wave-level reduce (64 lanes, all same m): LSE merge + min
    #pragma unroll
    for (int off = 32; off > 0; off >>= 1) {
        float om = __shfl_xor(mrun, off);
        float oS = __shfl_xor(S, off);
        float nm = fminf(mrun, om);
        S = S * exp2f(K10 * (nm - mrun)) + oS * exp2f(K10 * (nm - om));
        mrun = nm;
    }

    // --- combine the two waves of each m-group via LDS
    __shared__ float pm[16], pS[16];
    const int wid = tid >> 6;          // 0..15 (wave -> m = wid>>1)
    if ((tid & 63) == 0) { pm[wid] = mrun; pS[wid] = S; }
    __syncthreads();
    if (tid < 8) {
        const float m0 = pm[2 * tid], S0 = pS[2 * tid];
        const float m1 = pm[2 * tid + 1], S1 = pS[2 * tid + 1];
        const float nm = fminf(m0, m1);
        const float Sx = S0 * exp2f(K10 * (nm - m0)) + S1 * exp2f(K10 * (nm - m1));
        const int o = (b << 8) + (n << 3) + tid;
        out[o] = expf(-nm + 0.1f * logf(Sx));
        out[2048 + o] = sqrtf(fmaxf(nm, 0.0f));
    }
}

extern "C" void kernel_launch(void* const* d_in, const int* in_sizes, int n_in,
                              void* d_out, int out_size, void* d_ws, size_t ws_size,
                              hipStream_t stream) {
    const float* x = (const float*)d_in[0];   // (8,8,2048)
    const float* w = (const float*)d_in[1];   // (32,8,32)
    float* out = (float*)d_out;               // 4096 floats
    hipLaunchKernelGGL(shapelet_kernel, dim3(256), dim3(1024), 0, stream, x, w, out);
}